// Round 9
// baseline (73.922 us; speedup 1.0000x reference)
//
#include <hip/hip_runtime.h>
#include <hip/hip_bf16.h>

#define NN 2048
#define FIN 512
#define FOUT 128
#define ALPHAV 0.2f
#define LOG2E 1.44269504088896340736f

typedef __attribute__((ext_vector_type(8))) short bf16x8;
typedef __attribute__((ext_vector_type(4))) float f32x4;
typedef __attribute__((ext_vector_type(4))) int i32x4;

__device__ __forceinline__ unsigned cvt_pk_bf16(float lo, float hi) {
    unsigned r;
    asm("v_cvt_pk_bf16_f32 %0, %1, %2" : "=v"(r) : "v"(lo), "v"(hi));
    return r;   // low16 = bf16(lo), high16 = bf16(hi), RNE
}

__device__ __forceinline__ unsigned short f32_to_bf16(float f) {
    unsigned int u = __float_as_uint(f);
    unsigned int r = (u + 0x7FFFu + ((u >> 16) & 1u)) >> 16;   // RNE
    return (unsigned short)r;
}

// ---------------- Kernel S: {adj -> byte-mask} stream + W-repack tail ----------------
// grid = 2048 (mask) + 32 (wrep) blocks, 256 threads.
// Mask path: block = 4 rows (one per wave). Lane l owns ints [32l, 32l+32) of its row
// (contiguous 128 B): 8 independent nontemporal dwordx4 loads hoisted into registers,
// 32 compare-bits packed into ONE dword, one coalesced dword store (wave = 256 B).
// NT loads skip L3 allocation -> no dirty-line eviction/writeback tax from the
// harness's 268 MB poison fill.
__global__ void __launch_bounds__(256, 4) k_stream(const int* __restrict__ adj,
                                                   const int* __restrict__ d1p,
                                                   const int* __restrict__ d2p,
                                                   const float* __restrict__ W,
                                                   unsigned char* __restrict__ maskb,
                                                   unsigned short* __restrict__ whi,
                                                   unsigned short* __restrict__ wlo) {
    int tid = threadIdx.x;
    int wv = tid >> 6, l = tid & 63;

    if (blockIdx.x < 2048) {
        int d1 = d1p[0], d2 = d2p[0];
        int row = blockIdx.x * 4 + wv;                    // b*2048 + i
        const i32x4* ap = (const i32x4*)(adj + (size_t)row * NN) + l * 8;
        i32x4 v0 = __builtin_nontemporal_load(ap + 0);
        i32x4 v1 = __builtin_nontemporal_load(ap + 1);
        i32x4 v2 = __builtin_nontemporal_load(ap + 2);
        i32x4 v3 = __builtin_nontemporal_load(ap + 3);
        i32x4 v4 = __builtin_nontemporal_load(ap + 4);
        i32x4 v5 = __builtin_nontemporal_load(ap + 5);
        i32x4 v6 = __builtin_nontemporal_load(ap + 6);
        i32x4 v7 = __builtin_nontemporal_load(ap + 7);
        i32x4 vv[8] = {v0, v1, v2, v3, v4, v5, v6, v7};
        unsigned m = 0;
#pragma unroll
        for (int k = 0; k < 8; k++) {
            unsigned nib = 0;
            nib |= (vv[k].x == d1 || vv[k].x == d2) ? 1u : 0u;
            nib |= (vv[k].y == d1 || vv[k].y == d2) ? 2u : 0u;
            nib |= (vv[k].z == d1 || vv[k].z == d2) ? 4u : 0u;
            nib |= (vv[k].w == d1 || vv[k].w == d2) ? 8u : 0u;
            m |= nib << (k * 4);
        }
        ((unsigned*)(maskb + (size_t)row * 256))[l] = m;
        return;
    }

    // ---- W repack tail: 32 blocks x 4 subunits = 128 (kt,t_o) tiles ----
    {
        int idx = (blockIdx.x - 2048) * 4 + wv;
        int kt = idx >> 3;
        int t_o = idx & 7;
        int lr = l & 15, lg = l >> 4;
        unsigned short vh[8], vl[8];
#pragma unroll
        for (int jj = 0; jj < 8; jj++) {
            float f = W[(size_t)(kt * 32 + lg * 8 + jj) * FOUT + t_o * 16 + lr];
            unsigned short h = f32_to_bf16(f);
            float hf = __uint_as_float(((unsigned)h) << 16);
            vh[jj] = h;
            vl[jj] = f32_to_bf16(f - hf);
        }
        size_t o = ((size_t)(kt * 8 + t_o) * 64 + l) * 8;
        *(uint4*)(whi + o) = *(const uint4*)vh;
        *(uint4*)(wlo + o) = *(const uint4*)vl;
    }
}

// ---------------- Kernel H: h = x@W via split-bf16 MFMA; t1/t2; frag repack ----------------
// grid = 8192/16 = 512 blocks, 256 threads (4 waves).
// Block owns 16 rows x 128 cols; wave wv owns o-tiles {2wv, 2wv+1}.
// t1/t2 stored PRE-SCALED by log2(e) for k_attn's exp2.
__global__ void __launch_bounds__(256) k_h(const float* __restrict__ x,
                                           const unsigned short* __restrict__ whi,
                                           const unsigned short* __restrict__ wlo,
                                           const float* __restrict__ a1,
                                           const float* __restrict__ a2,
                                           unsigned short* __restrict__ hb,
                                           float* __restrict__ t1,
                                           float* __restrict__ t2) {
    __shared__ float lds_t1[4][16];
    __shared__ float lds_t2[4][16];
    int blk = blockIdx.x;
    int tid = threadIdx.x;
    int wv = tid >> 6, l = tid & 63;
    int lr = l & 15, lg = l >> 4;
    int row0 = blk * 16;

    const float* xp = x + (size_t)(row0 + lr) * FIN + lg * 8;
    const unsigned short* wb = whi + (size_t)(2 * wv) * 512 + l * 8;
    const unsigned short* lb = wlo + (size_t)(2 * wv) * 512 + l * 8;

    f32x4 acc0 = {0.f, 0.f, 0.f, 0.f};
    f32x4 acc1 = {0.f, 0.f, 0.f, 0.f};

#pragma unroll 2
    for (int kt = 0; kt < FIN / 32; kt++) {
        float4 xa = *(const float4*)(xp + kt * 32);
        float4 xb = *(const float4*)(xp + kt * 32 + 4);
        bf16x8 wh0 = *(const bf16x8*)(wb + (size_t)kt * 4096);
        bf16x8 wh1 = *(const bf16x8*)(wb + (size_t)kt * 4096 + 512);
        bf16x8 wl0 = *(const bf16x8*)(lb + (size_t)kt * 4096);
        bf16x8 wl1 = *(const bf16x8*)(lb + (size_t)kt * 4096 + 512);

        float f[8] = {xa.x, xa.y, xa.z, xa.w, xb.x, xb.y, xb.z, xb.w};
        unsigned uh[4], ul[4];
#pragma unroll
        for (int w = 0; w < 4; w++) {
            uh[w] = cvt_pk_bf16(f[2 * w], f[2 * w + 1]);
            float r0 = f[2 * w]     - __uint_as_float(uh[w] << 16);
            float r1 = f[2 * w + 1] - __uint_as_float(uh[w] & 0xffff0000u);
            ul[w] = cvt_pk_bf16(r0, r1);
        }
        bf16x8 xh = *(const bf16x8*)uh;
        bf16x8 xl = *(const bf16x8*)ul;

        acc0 = __builtin_amdgcn_mfma_f32_16x16x32_bf16(xh, wh0, acc0, 0, 0, 0);
        acc0 = __builtin_amdgcn_mfma_f32_16x16x32_bf16(xl, wh0, acc0, 0, 0, 0);
        acc0 = __builtin_amdgcn_mfma_f32_16x16x32_bf16(xh, wl0, acc0, 0, 0, 0);
        acc1 = __builtin_amdgcn_mfma_f32_16x16x32_bf16(xh, wh1, acc1, 0, 0, 0);
        acc1 = __builtin_amdgcn_mfma_f32_16x16x32_bf16(xl, wh1, acc1, 0, 0, 0);
        acc1 = __builtin_amdgcn_mfma_f32_16x16x32_bf16(xh, wl1, acc1, 0, 0, 0);
    }

    // t1/t2 partials + LDS combine (pre-scaled by log2e)
    {
        float a10 = a1[(2 * wv) * 16 + lr], a11 = a1[(2 * wv + 1) * 16 + lr];
        float a20 = a2[(2 * wv) * 16 + lr], a21 = a2[(2 * wv + 1) * 16 + lr];
        float p1[4], p2[4];
#pragma unroll
        for (int r = 0; r < 4; r++) {
            p1[r] = acc0[r] * a10 + acc1[r] * a11;
            p2[r] = acc0[r] * a20 + acc1[r] * a21;
        }
#pragma unroll
        for (int off = 1; off < 16; off <<= 1) {
#pragma unroll
            for (int r = 0; r < 4; r++) {
                p1[r] += __shfl_xor(p1[r], off);
                p2[r] += __shfl_xor(p2[r], off);
            }
        }
        if (lr == 0) {
#pragma unroll
            for (int r = 0; r < 4; r++) {
                lds_t1[wv][lg * 4 + r] = p1[r];
                lds_t2[wv][lg * 4 + r] = p2[r];
            }
        }
        __syncthreads();
        if (tid < 16) {
            t1[row0 + tid] = (lds_t1[0][tid] + lds_t1[1][tid] + lds_t1[2][tid] + lds_t1[3][tid]) * LOG2E;
            t2[row0 + tid] = (lds_t2[0][tid] + lds_t2[1][tid] + lds_t2[2][tid] + lds_t2[3][tid]) * LOG2E;
        }
    }

    // repack h -> B-fragment layout via intra-wave shuffles
    {
        size_t jtg = (size_t)(blk >> 1);
        int srcbase = (2 * (lg & 1)) * 16 + lr;
        bool active = (lg >> 1) == (blk & 1);
#pragma unroll
        for (int t = 0; t < 2; t++) {
            f32x4 a = t == 0 ? acc0 : acc1;
            unsigned p0 = cvt_pk_bf16(a[0], a[1]);
            unsigned p1 = cvt_pk_bf16(a[2], a[3]);
            unsigned g0 = __shfl((int)p0, srcbase);
            unsigned g1 = __shfl((int)p1, srcbase);
            unsigned g2 = __shfl((int)p0, srcbase + 16);
            unsigned g3 = __shfl((int)p1, srcbase + 16);
            if (active) {
                uint4 v = {g0, g1, g2, g3};
                int t_o = 2 * wv + t;
                *(uint4*)(hb + (jtg * 8 + t_o) * 512 + l * 8) = v;
            }
        }
    }
}

// ---------------- Kernel B: fused masked-softmax attention + PV (MFMA) ----------------
// grid = B*N/16 = 512 blocks, 512 threads (8 waves).
// Wave wv handles j-tiles jt = wv + 8*it (it=0..7, fully unrolled), all 8 o-tiles.
// Mask bytes prefetched into registers. No online max (logits bounded in log2 domain;
// masked -> p=0 exactly). Cross-wave combine = pure sum, two-phase LDS.
__global__ void __launch_bounds__(512, 4) k_attn(const unsigned char* __restrict__ maskb,
                                                 const float* __restrict__ t1g,
                                                 const float* __restrict__ t2g,
                                                 const unsigned short* __restrict__ hb,
                                                 float* __restrict__ out) {
    __shared__ __align__(16) float accbuf[4][16][132];   // 33792 B
    __shared__ float lds_s[8][16];
    __shared__ float lds_inv[16];

    int blk = blockIdx.x;
    int b = blk >> 7;
    int i0 = (blk & 127) * 16;
    int tid = threadIdx.x;
    int wv = tid >> 6;            // 0..7
    int l = tid & 63;
    int lr = l & 15, lg = l >> 4;

    float t1v = t1g[b * NN + i0 + lr];                       // pre-scaled by log2e
    const float* t2p = t2g + b * NN + lg * 8;                // pre-scaled by log2e
    const unsigned short* hbbase = hb + (size_t)b * 64 * 4096 + (size_t)l * 8;
    const unsigned char* mrow = maskb + (size_t)(b * NN + i0 + lr) * 256 + lg;

    unsigned mby[8];
#pragma unroll
    for (int it = 0; it < 8; it++)
        mby[it] = mrow[(wv + it * 8) * 4];

    float s = 0.f;
    f32x4 acc[8];
#pragma unroll
    for (int t = 0; t < 8; t++) acc[t] = (f32x4){0.f, 0.f, 0.f, 0.f};

#pragma unroll
    for (int it = 0; it < 8; it++) {
        int jt = wv + it * 8;
        float4 tb0 = *(const float4*)(t2p + jt * 32);
        float4 tb1 = *(const float4*)(t2p + jt * 32 + 4);
        bf16x8 hf[8];
#pragma unroll
        for (int t = 0; t < 8; t++)
            hf[t] = *(const bf16x8*)(hbbase + (size_t)jt * 4096 + t * 512);

        unsigned mbyte = mby[it];
        float tv[8] = {tb0.x, tb0.y, tb0.z, tb0.w, tb1.x, tb1.y, tb1.z, tb1.w};
        float p[8];
        float psum = 0.f;
#pragma unroll
        for (int jj = 0; jj < 8; jj++) {
            float v = t1v + tv[jj];
            float e = fmaxf(v, ALPHAV * v);              // leaky relu (log2 domain)
            float ex = __builtin_amdgcn_exp2f(e);
            p[jj] = (mbyte & (1u << jj)) ? ex : 0.f;
            psum += p[jj];
        }
        s += psum;

        unsigned u[4];
#pragma unroll
        for (int w = 0; w < 4; w++) u[w] = cvt_pk_bf16(p[2 * w], p[2 * w + 1]);
        bf16x8 pa = *(const bf16x8*)u;
#pragma unroll
        for (int t = 0; t < 8; t++)
            acc[t] = __builtin_amdgcn_mfma_f32_16x16x32_bf16(pa, hf[t], acc[t], 0, 0, 0);
    }

    // ---- cross-wave sum combine ----
    s += __shfl_xor(s, 16);
    s += __shfl_xor(s, 32);
    if (l < 16) lds_s[wv][lr] = s;

    if (wv < 4) {
#pragma unroll
        for (int t = 0; t < 8; t++)
#pragma unroll
            for (int r = 0; r < 4; r++)
                accbuf[wv][lg * 4 + r][t * 16 + lr] = acc[t][r];
    }
    __syncthreads();
    if (wv >= 4) {
#pragma unroll
        for (int t = 0; t < 8; t++)
#pragma unroll
            for (int r = 0; r < 4; r++)
                accbuf[wv - 4][lg * 4 + r][t * 16 + lr] += acc[t][r];
    }
    if (tid < 16) {
        float st = 0.f;
#pragma unroll
        for (int w = 0; w < 8; w++) st += lds_s[w][tid];
        lds_inv[tid] = 1.0f / st;
    }
    __syncthreads();

    {
        int row = tid >> 5;
        int c4 = (tid & 31) * 4;
        float4 s0 = *(const float4*)&accbuf[0][row][c4];
        float4 s1 = *(const float4*)&accbuf[1][row][c4];
        float4 s2 = *(const float4*)&accbuf[2][row][c4];
        float4 s3 = *(const float4*)&accbuf[3][row][c4];
        float inv = lds_inv[row];
        float4 o;
        o.x = (s0.x + s1.x + s2.x + s3.x) * inv;
        o.y = (s0.y + s1.y + s2.y + s3.y) * inv;
        o.z = (s0.z + s1.z + s2.z + s3.z) * inv;
        o.w = (s0.w + s1.w + s2.w + s3.w) * inv;
        *(float4*)&out[((size_t)b * NN + i0 + row) * FOUT + c4] = o;
    }
}

extern "C" void kernel_launch(void* const* d_in, const int* in_sizes, int n_in,
                              void* d_out, int out_size, void* d_ws, size_t ws_size,
                              hipStream_t stream) {
    const float* x  = (const float*)d_in[0];
    const float* W  = (const float*)d_in[1];
    const float* a1 = (const float*)d_in[2];
    const float* a2 = (const float*)d_in[3];
    const int* adj  = (const int*)d_in[4];
    // d_in[5] = adj_tree (unused by reference forward)
    const int* d1p  = (const int*)d_in[6];
    const int* d2p  = (const int*)d_in[7];
    float* out = (float*)d_out;

    char* ws = (char*)d_ws;
    unsigned short* hbuf = (unsigned short*)(ws);                       // 2 MB
    float* t1            = (float*)(ws + 2u * 1024 * 1024);             // 32 KB
    float* t2            = (float*)(ws + 2u * 1024 * 1024 + 32 * 1024); // 32 KB
    unsigned short* whi  = (unsigned short*)(ws + 2u * 1024 * 1024 + 64 * 1024);  // 128 KB
    unsigned short* wlo  = (unsigned short*)(ws + 2u * 1024 * 1024 + 192 * 1024); // 128 KB
    unsigned char* maskb = (unsigned char*)(ws + 2u * 1024 * 1024 + 320 * 1024);  // 2 MB

    k_stream<<<dim3(2080), dim3(256), 0, stream>>>(adj, d1p, d2p, W, maskb, whi, wlo);
    k_h<<<dim3(512), dim3(256), 0, stream>>>(x, whi, wlo, a1, a2, hbuf, t1, t2);
    k_attn<<<dim3(512), dim3(512), 0, stream>>>(maskb, t1, t2, hbuf, out);
}

// Round 10
// 50.170 us; speedup vs baseline: 1.4734x; 1.4734x over previous
//
#include <hip/hip_runtime.h>
#include <hip/hip_bf16.h>

#define NN 2048
#define FIN 512
#define FOUT 128
#define ALPHAV 0.2f
#define LOG2E 1.44269504088896340736f

typedef __attribute__((ext_vector_type(8))) short bf16x8;
typedef __attribute__((ext_vector_type(4))) float f32x4;
typedef __attribute__((ext_vector_type(4))) int i32x4;

__device__ __forceinline__ unsigned cvt_pk_bf16(float lo, float hi) {
    unsigned r;
    asm("v_cvt_pk_bf16_f32 %0, %1, %2" : "=v"(r) : "v"(lo), "v"(hi));
    return r;   // low16 = bf16(lo), high16 = bf16(hi), RNE
}

__device__ __forceinline__ unsigned short f32_to_bf16(float f) {
    unsigned int u = __float_as_uint(f);
    unsigned int r = (u + 0x7FFFu + ((u >> 16) & 1u)) >> 16;   // RNE
    return (unsigned short)r;
}

__device__ __forceinline__ unsigned pack8(const i32x4* v, int d1, int d2) {
    unsigned m = 0;
#pragma unroll
    for (int k = 0; k < 8; k++) {
        unsigned nib = 0;
        nib |= (v[k].x == d1 || v[k].x == d2) ? 1u : 0u;
        nib |= (v[k].y == d1 || v[k].y == d2) ? 2u : 0u;
        nib |= (v[k].z == d1 || v[k].z == d2) ? 4u : 0u;
        nib |= (v[k].w == d1 || v[k].w == d2) ? 8u : 0u;
        m |= nib << (k * 4);
    }
    return m;
}

// ---------------- Kernel S: {adj -> byte-mask} stream + W-repack tail ----------------
// grid = 1024 (mask) + 32 (wrep) blocks, 256 threads.
// Mask path: wave handles 2 rows; lane l owns ints [32l,32l+32) of each row:
// 16 independent cached dwordx4 loads hoisted into registers (deep MLP), then two
// coalesced dword stores (256 B/wave each).
__global__ void __launch_bounds__(256) k_stream(const int* __restrict__ adj,
                                                const int* __restrict__ d1p,
                                                const int* __restrict__ d2p,
                                                const float* __restrict__ W,
                                                unsigned char* __restrict__ maskb,
                                                unsigned short* __restrict__ whi,
                                                unsigned short* __restrict__ wlo) {
    int tid = threadIdx.x;
    int wv = tid >> 6, l = tid & 63;

    if (blockIdx.x < 1024) {
        int d1 = d1p[0], d2 = d2p[0];
        int row0 = blockIdx.x * 8 + wv * 2;               // 8 rows/block, 2 rows/wave
        const i32x4* ap0 = (const i32x4*)(adj + (size_t)row0 * NN) + l * 8;
        const i32x4* ap1 = (const i32x4*)(adj + (size_t)(row0 + 1) * NN) + l * 8;
        i32x4 a0 = ap0[0], a1 = ap0[1], a2 = ap0[2], a3 = ap0[3];
        i32x4 a4 = ap0[4], a5 = ap0[5], a6 = ap0[6], a7 = ap0[7];
        i32x4 b0 = ap1[0], b1 = ap1[1], b2 = ap1[2], b3 = ap1[3];
        i32x4 b4 = ap1[4], b5 = ap1[5], b6 = ap1[6], b7 = ap1[7];
        i32x4 va[8] = {a0, a1, a2, a3, a4, a5, a6, a7};
        i32x4 vb[8] = {b0, b1, b2, b3, b4, b5, b6, b7};
        unsigned m0 = pack8(va, d1, d2);
        unsigned m1 = pack8(vb, d1, d2);
        ((unsigned*)(maskb + (size_t)row0 * 256))[l] = m0;
        ((unsigned*)(maskb + (size_t)(row0 + 1) * 256))[l] = m1;
        return;
    }

    // ---- W repack tail: 32 blocks x 4 subunits = 128 (kt,t_o) tiles ----
    {
        int idx = (blockIdx.x - 1024) * 4 + wv;
        int kt = idx >> 3;
        int t_o = idx & 7;
        int lr = l & 15, lg = l >> 4;
        unsigned short vh[8], vl[8];
#pragma unroll
        for (int jj = 0; jj < 8; jj++) {
            float f = W[(size_t)(kt * 32 + lg * 8 + jj) * FOUT + t_o * 16 + lr];
            unsigned short h = f32_to_bf16(f);
            float hf = __uint_as_float(((unsigned)h) << 16);
            vh[jj] = h;
            vl[jj] = f32_to_bf16(f - hf);
        }
        size_t o = ((size_t)(kt * 8 + t_o) * 64 + l) * 8;
        *(uint4*)(whi + o) = *(const uint4*)vh;
        *(uint4*)(wlo + o) = *(const uint4*)vl;
    }
}

// ---------------- Kernel H: h = x@W via split-bf16 MFMA; t1/t2; frag repack ----------------
// grid = 8192/16 = 512 blocks, 256 threads (4 waves).
// Block owns 16 rows x 128 cols; wave wv owns o-tiles {2wv, 2wv+1}.
// t1/t2 stored PRE-SCALED by log2(e) for k_attn's exp2.
__global__ void __launch_bounds__(256) k_h(const float* __restrict__ x,
                                           const unsigned short* __restrict__ whi,
                                           const unsigned short* __restrict__ wlo,
                                           const float* __restrict__ a1,
                                           const float* __restrict__ a2,
                                           unsigned short* __restrict__ hb,
                                           float* __restrict__ t1,
                                           float* __restrict__ t2) {
    __shared__ float lds_t1[4][16];
    __shared__ float lds_t2[4][16];
    int blk = blockIdx.x;
    int tid = threadIdx.x;
    int wv = tid >> 6, l = tid & 63;
    int lr = l & 15, lg = l >> 4;
    int row0 = blk * 16;

    const float* xp = x + (size_t)(row0 + lr) * FIN + lg * 8;
    const unsigned short* wb = whi + (size_t)(2 * wv) * 512 + l * 8;
    const unsigned short* lb = wlo + (size_t)(2 * wv) * 512 + l * 8;

    f32x4 acc0 = {0.f, 0.f, 0.f, 0.f};
    f32x4 acc1 = {0.f, 0.f, 0.f, 0.f};

#pragma unroll 2
    for (int kt = 0; kt < FIN / 32; kt++) {
        float4 xa = *(const float4*)(xp + kt * 32);
        float4 xb = *(const float4*)(xp + kt * 32 + 4);
        bf16x8 wh0 = *(const bf16x8*)(wb + (size_t)kt * 4096);
        bf16x8 wh1 = *(const bf16x8*)(wb + (size_t)kt * 4096 + 512);
        bf16x8 wl0 = *(const bf16x8*)(lb + (size_t)kt * 4096);
        bf16x8 wl1 = *(const bf16x8*)(lb + (size_t)kt * 4096 + 512);

        float f[8] = {xa.x, xa.y, xa.z, xa.w, xb.x, xb.y, xb.z, xb.w};
        unsigned uh[4], ul[4];
#pragma unroll
        for (int w = 0; w < 4; w++) {
            uh[w] = cvt_pk_bf16(f[2 * w], f[2 * w + 1]);
            float r0 = f[2 * w]     - __uint_as_float(uh[w] << 16);
            float r1 = f[2 * w + 1] - __uint_as_float(uh[w] & 0xffff0000u);
            ul[w] = cvt_pk_bf16(r0, r1);
        }
        bf16x8 xh = *(const bf16x8*)uh;
        bf16x8 xl = *(const bf16x8*)ul;

        acc0 = __builtin_amdgcn_mfma_f32_16x16x32_bf16(xh, wh0, acc0, 0, 0, 0);
        acc0 = __builtin_amdgcn_mfma_f32_16x16x32_bf16(xl, wh0, acc0, 0, 0, 0);
        acc0 = __builtin_amdgcn_mfma_f32_16x16x32_bf16(xh, wl0, acc0, 0, 0, 0);
        acc1 = __builtin_amdgcn_mfma_f32_16x16x32_bf16(xh, wh1, acc1, 0, 0, 0);
        acc1 = __builtin_amdgcn_mfma_f32_16x16x32_bf16(xl, wh1, acc1, 0, 0, 0);
        acc1 = __builtin_amdgcn_mfma_f32_16x16x32_bf16(xh, wl1, acc1, 0, 0, 0);
    }

    // t1/t2 partials + LDS combine (pre-scaled by log2e)
    {
        float a10 = a1[(2 * wv) * 16 + lr], a11 = a1[(2 * wv + 1) * 16 + lr];
        float a20 = a2[(2 * wv) * 16 + lr], a21 = a2[(2 * wv + 1) * 16 + lr];
        float p1[4], p2[4];
#pragma unroll
        for (int r = 0; r < 4; r++) {
            p1[r] = acc0[r] * a10 + acc1[r] * a11;
            p2[r] = acc0[r] * a20 + acc1[r] * a21;
        }
#pragma unroll
        for (int off = 1; off < 16; off <<= 1) {
#pragma unroll
            for (int r = 0; r < 4; r++) {
                p1[r] += __shfl_xor(p1[r], off);
                p2[r] += __shfl_xor(p2[r], off);
            }
        }
        if (lr == 0) {
#pragma unroll
            for (int r = 0; r < 4; r++) {
                lds_t1[wv][lg * 4 + r] = p1[r];
                lds_t2[wv][lg * 4 + r] = p2[r];
            }
        }
        __syncthreads();
        if (tid < 16) {
            t1[row0 + tid] = (lds_t1[0][tid] + lds_t1[1][tid] + lds_t1[2][tid] + lds_t1[3][tid]) * LOG2E;
            t2[row0 + tid] = (lds_t2[0][tid] + lds_t2[1][tid] + lds_t2[2][tid] + lds_t2[3][tid]) * LOG2E;
        }
    }

    // repack h -> B-fragment layout via intra-wave shuffles
    {
        size_t jtg = (size_t)(blk >> 1);
        int srcbase = (2 * (lg & 1)) * 16 + lr;
        bool active = (lg >> 1) == (blk & 1);
#pragma unroll
        for (int t = 0; t < 2; t++) {
            f32x4 a = t == 0 ? acc0 : acc1;
            unsigned p0 = cvt_pk_bf16(a[0], a[1]);
            unsigned p1 = cvt_pk_bf16(a[2], a[3]);
            unsigned g0 = __shfl((int)p0, srcbase);
            unsigned g1 = __shfl((int)p1, srcbase);
            unsigned g2 = __shfl((int)p0, srcbase + 16);
            unsigned g3 = __shfl((int)p1, srcbase + 16);
            if (active) {
                uint4 v = {g0, g1, g2, g3};
                int t_o = 2 * wv + t;
                *(uint4*)(hb + (jtg * 8 + t_o) * 512 + l * 8) = v;
            }
        }
    }
}

// ---------------- Kernel B: fused masked-softmax attention + PV (MFMA) ----------------
// grid = B*N/16 = 512 blocks, 512 threads (8 waves).
// Wave wv handles j-tiles jt = wv + 8*it (it=0..7, fully unrolled), all 8 o-tiles.
// Mask bytes prefetched into registers. No online max (logits bounded in log2 domain;
// masked -> p=0 exactly). Cross-wave combine = pure sum, two-phase LDS.
__global__ void __launch_bounds__(512, 4) k_attn(const unsigned char* __restrict__ maskb,
                                                 const float* __restrict__ t1g,
                                                 const float* __restrict__ t2g,
                                                 const unsigned short* __restrict__ hb,
                                                 float* __restrict__ out) {
    __shared__ __align__(16) float accbuf[4][16][132];   // 33792 B
    __shared__ float lds_s[8][16];
    __shared__ float lds_inv[16];

    int blk = blockIdx.x;
    int b = blk >> 7;
    int i0 = (blk & 127) * 16;
    int tid = threadIdx.x;
    int wv = tid >> 6;            // 0..7
    int l = tid & 63;
    int lr = l & 15, lg = l >> 4;

    float t1v = t1g[b * NN + i0 + lr];                       // pre-scaled by log2e
    const float* t2p = t2g + b * NN + lg * 8;                // pre-scaled by log2e
    const unsigned short* hbbase = hb + (size_t)b * 64 * 4096 + (size_t)l * 8;
    const unsigned char* mrow = maskb + (size_t)(b * NN + i0 + lr) * 256 + lg;

    unsigned mby[8];
#pragma unroll
    for (int it = 0; it < 8; it++)
        mby[it] = mrow[(wv + it * 8) * 4];

    float s = 0.f;
    f32x4 acc[8];
#pragma unroll
    for (int t = 0; t < 8; t++) acc[t] = (f32x4){0.f, 0.f, 0.f, 0.f};

#pragma unroll
    for (int it = 0; it < 8; it++) {
        int jt = wv + it * 8;
        float4 tb0 = *(const float4*)(t2p + jt * 32);
        float4 tb1 = *(const float4*)(t2p + jt * 32 + 4);
        bf16x8 hf[8];
#pragma unroll
        for (int t = 0; t < 8; t++)
            hf[t] = *(const bf16x8*)(hbbase + (size_t)jt * 4096 + t * 512);

        unsigned mbyte = mby[it];
        float tv[8] = {tb0.x, tb0.y, tb0.z, tb0.w, tb1.x, tb1.y, tb1.z, tb1.w};
        float p[8];
        float psum = 0.f;
#pragma unroll
        for (int jj = 0; jj < 8; jj++) {
            float v = t1v + tv[jj];
            float e = fmaxf(v, ALPHAV * v);              // leaky relu (log2 domain)
            float ex = __builtin_amdgcn_exp2f(e);
            p[jj] = (mbyte & (1u << jj)) ? ex : 0.f;
            psum += p[jj];
        }
        s += psum;

        unsigned u[4];
#pragma unroll
        for (int w = 0; w < 4; w++) u[w] = cvt_pk_bf16(p[2 * w], p[2 * w + 1]);
        bf16x8 pa = *(const bf16x8*)u;
#pragma unroll
        for (int t = 0; t < 8; t++)
            acc[t] = __builtin_amdgcn_mfma_f32_16x16x32_bf16(pa, hf[t], acc[t], 0, 0, 0);
    }

    // ---- cross-wave sum combine ----
    s += __shfl_xor(s, 16);
    s += __shfl_xor(s, 32);
    if (l < 16) lds_s[wv][lr] = s;

    if (wv < 4) {
#pragma unroll
        for (int t = 0; t < 8; t++)
#pragma unroll
            for (int r = 0; r < 4; r++)
                accbuf[wv][lg * 4 + r][t * 16 + lr] = acc[t][r];
    }
    __syncthreads();
    if (wv >= 4) {
#pragma unroll
        for (int t = 0; t < 8; t++)
#pragma unroll
            for (int r = 0; r < 4; r++)
                accbuf[wv - 4][lg * 4 + r][t * 16 + lr] += acc[t][r];
    }
    if (tid < 16) {
        float st = 0.f;
#pragma unroll
        for (int w = 0; w < 8; w++) st += lds_s[w][tid];
        lds_inv[tid] = 1.0f / st;
    }
    __syncthreads();

    {
        int row = tid >> 5;
        int c4 = (tid & 31) * 4;
        float4 s0 = *(const float4*)&accbuf[0][row][c4];
        float4 s1 = *(const float4*)&accbuf[1][row][c4];
        float4 s2 = *(const float4*)&accbuf[2][row][c4];
        float4 s3 = *(const float4*)&accbuf[3][row][c4];
        float inv = lds_inv[row];
        float4 o;
        o.x = (s0.x + s1.x + s2.x + s3.x) * inv;
        o.y = (s0.y + s1.y + s2.y + s3.y) * inv;
        o.z = (s0.z + s1.z + s2.z + s3.z) * inv;
        o.w = (s0.w + s1.w + s2.w + s3.w) * inv;
        *(float4*)&out[((size_t)b * NN + i0 + row) * FOUT + c4] = o;
    }
}

extern "C" void kernel_launch(void* const* d_in, const int* in_sizes, int n_in,
                              void* d_out, int out_size, void* d_ws, size_t ws_size,
                              hipStream_t stream) {
    const float* x  = (const float*)d_in[0];
    const float* W  = (const float*)d_in[1];
    const float* a1 = (const float*)d_in[2];
    const float* a2 = (const float*)d_in[3];
    const int* adj  = (const int*)d_in[4];
    // d_in[5] = adj_tree (unused by reference forward)
    const int* d1p  = (const int*)d_in[6];
    const int* d2p  = (const int*)d_in[7];
    float* out = (float*)d_out;

    char* ws = (char*)d_ws;
    unsigned short* hbuf = (unsigned short*)(ws);                       // 2 MB
    float* t1            = (float*)(ws + 2u * 1024 * 1024);             // 32 KB
    float* t2            = (float*)(ws + 2u * 1024 * 1024 + 32 * 1024); // 32 KB
    unsigned short* whi  = (unsigned short*)(ws + 2u * 1024 * 1024 + 64 * 1024);  // 128 KB
    unsigned short* wlo  = (unsigned short*)(ws + 2u * 1024 * 1024 + 192 * 1024); // 128 KB
    unsigned char* maskb = (unsigned char*)(ws + 2u * 1024 * 1024 + 320 * 1024);  // 2 MB

    k_stream<<<dim3(1056), dim3(256), 0, stream>>>(adj, d1p, d2p, W, maskb, whi, wlo);
    k_h<<<dim3(512), dim3(256), 0, stream>>>(x, whi, wlo, a1, a2, hbuf, t1, t2);
    k_attn<<<dim3(512), dim3(512), 0, stream>>>(maskb, t1, t2, hbuf, out);
}

// Round 11
// 46.920 us; speedup vs baseline: 1.5755x; 1.0693x over previous
//
#include <hip/hip_runtime.h>
#include <hip/hip_bf16.h>

#define NN 2048
#define FIN 512
#define FOUT 128
#define ALPHAV 0.2f
#define LOG2E 1.44269504088896340736f

typedef __attribute__((ext_vector_type(8))) short bf16x8;
typedef __attribute__((ext_vector_type(4))) float f32x4;

__device__ __forceinline__ unsigned cvt_pk_bf16(float lo, float hi) {
    unsigned r;
    asm("v_cvt_pk_bf16_f32 %0, %1, %2" : "=v"(r) : "v"(lo), "v"(hi));
    return r;   // low16 = bf16(lo), high16 = bf16(hi), RNE
}

__device__ __forceinline__ unsigned short f32_to_bf16(float f) {
    unsigned int u = __float_as_uint(f);
    unsigned int r = (u + 0x7FFFu + ((u >> 16) & 1u)) >> 16;   // RNE
    return (unsigned short)r;
}

// ---------------- Kernel W: repack W -> bf16 hi/lo MFMA-B fragments ----------------
// grid = 128 blocks (16 kt x 8 t_o), 64 threads.
__global__ void k_wrep(const float* __restrict__ W,
                       unsigned short* __restrict__ whi,
                       unsigned short* __restrict__ wlo) {
    int kt = blockIdx.x >> 3;
    int t_o = blockIdx.x & 7;
    int l = threadIdx.x;
    int lr = l & 15, lg = l >> 4;
    unsigned short vh[8], vl[8];
#pragma unroll
    for (int jj = 0; jj < 8; jj++) {
        float f = W[(size_t)(kt * 32 + lg * 8 + jj) * FOUT + t_o * 16 + lr];
        unsigned short h = f32_to_bf16(f);
        float hf = __uint_as_float(((unsigned)h) << 16);
        vh[jj] = h;
        vl[jj] = f32_to_bf16(f - hf);
    }
    size_t o = ((size_t)(kt * 8 + t_o) * 64 + l) * 8;
    *(uint4*)(whi + o) = *(const uint4*)vh;
    *(uint4*)(wlo + o) = *(const uint4*)vl;
}

// ---------------- Kernel H: h = x@W via split-bf16 MFMA; t1/t2; frag repack ----------------
// grid = 8192/16 = 512 blocks, 256 threads (4 waves).
// Block owns 16 rows x 128 cols; wave wv owns o-tiles {2wv, 2wv+1}.
// t1/t2 stored PRE-SCALED by log2(e) for k_attn's exp2.
__global__ void __launch_bounds__(256) k_h(const float* __restrict__ x,
                                           const unsigned short* __restrict__ whi,
                                           const unsigned short* __restrict__ wlo,
                                           const float* __restrict__ a1,
                                           const float* __restrict__ a2,
                                           unsigned short* __restrict__ hb,
                                           float* __restrict__ t1,
                                           float* __restrict__ t2) {
    __shared__ float lds_t1[4][16];
    __shared__ float lds_t2[4][16];
    int blk = blockIdx.x;
    int tid = threadIdx.x;
    int wv = tid >> 6, l = tid & 63;
    int lr = l & 15, lg = l >> 4;
    int row0 = blk * 16;

    const float* xp = x + (size_t)(row0 + lr) * FIN + lg * 8;
    const unsigned short* wb = whi + (size_t)(2 * wv) * 512 + l * 8;
    const unsigned short* lb = wlo + (size_t)(2 * wv) * 512 + l * 8;

    f32x4 acc0 = {0.f, 0.f, 0.f, 0.f};
    f32x4 acc1 = {0.f, 0.f, 0.f, 0.f};

#pragma unroll 2
    for (int kt = 0; kt < FIN / 32; kt++) {
        float4 xa = *(const float4*)(xp + kt * 32);
        float4 xb = *(const float4*)(xp + kt * 32 + 4);
        bf16x8 wh0 = *(const bf16x8*)(wb + (size_t)kt * 4096);
        bf16x8 wh1 = *(const bf16x8*)(wb + (size_t)kt * 4096 + 512);
        bf16x8 wl0 = *(const bf16x8*)(lb + (size_t)kt * 4096);
        bf16x8 wl1 = *(const bf16x8*)(lb + (size_t)kt * 4096 + 512);

        float f[8] = {xa.x, xa.y, xa.z, xa.w, xb.x, xb.y, xb.z, xb.w};
        unsigned uh[4], ul[4];
#pragma unroll
        for (int w = 0; w < 4; w++) {
            uh[w] = cvt_pk_bf16(f[2 * w], f[2 * w + 1]);
            float r0 = f[2 * w]     - __uint_as_float(uh[w] << 16);
            float r1 = f[2 * w + 1] - __uint_as_float(uh[w] & 0xffff0000u);
            ul[w] = cvt_pk_bf16(r0, r1);
        }
        bf16x8 xh = *(const bf16x8*)uh;
        bf16x8 xl = *(const bf16x8*)ul;

        acc0 = __builtin_amdgcn_mfma_f32_16x16x32_bf16(xh, wh0, acc0, 0, 0, 0);
        acc0 = __builtin_amdgcn_mfma_f32_16x16x32_bf16(xl, wh0, acc0, 0, 0, 0);
        acc0 = __builtin_amdgcn_mfma_f32_16x16x32_bf16(xh, wl0, acc0, 0, 0, 0);
        acc1 = __builtin_amdgcn_mfma_f32_16x16x32_bf16(xh, wh1, acc1, 0, 0, 0);
        acc1 = __builtin_amdgcn_mfma_f32_16x16x32_bf16(xl, wh1, acc1, 0, 0, 0);
        acc1 = __builtin_amdgcn_mfma_f32_16x16x32_bf16(xh, wl1, acc1, 0, 0, 0);
    }

    // t1/t2 partials + LDS combine (pre-scaled by log2e)
    {
        float a10 = a1[(2 * wv) * 16 + lr], a11 = a1[(2 * wv + 1) * 16 + lr];
        float a20 = a2[(2 * wv) * 16 + lr], a21 = a2[(2 * wv + 1) * 16 + lr];
        float p1[4], p2[4];
#pragma unroll
        for (int r = 0; r < 4; r++) {
            p1[r] = acc0[r] * a10 + acc1[r] * a11;
            p2[r] = acc0[r] * a20 + acc1[r] * a21;
        }
#pragma unroll
        for (int off = 1; off < 16; off <<= 1) {
#pragma unroll
            for (int r = 0; r < 4; r++) {
                p1[r] += __shfl_xor(p1[r], off);
                p2[r] += __shfl_xor(p2[r], off);
            }
        }
        if (lr == 0) {
#pragma unroll
            for (int r = 0; r < 4; r++) {
                lds_t1[wv][lg * 4 + r] = p1[r];
                lds_t2[wv][lg * 4 + r] = p2[r];
            }
        }
        __syncthreads();
        if (tid < 16) {
            t1[row0 + tid] = (lds_t1[0][tid] + lds_t1[1][tid] + lds_t1[2][tid] + lds_t1[3][tid]) * LOG2E;
            t2[row0 + tid] = (lds_t2[0][tid] + lds_t2[1][tid] + lds_t2[2][tid] + lds_t2[3][tid]) * LOG2E;
        }
    }

    // repack h -> B-fragment layout via intra-wave shuffles
    {
        size_t jtg = (size_t)(blk >> 1);
        int srcbase = (2 * (lg & 1)) * 16 + lr;
        bool active = (lg >> 1) == (blk & 1);
#pragma unroll
        for (int t = 0; t < 2; t++) {
            f32x4 a = t == 0 ? acc0 : acc1;
            unsigned p0 = cvt_pk_bf16(a[0], a[1]);
            unsigned p1 = cvt_pk_bf16(a[2], a[3]);
            unsigned g0 = __shfl((int)p0, srcbase);
            unsigned g1 = __shfl((int)p1, srcbase);
            unsigned g2 = __shfl((int)p0, srcbase + 16);
            unsigned g3 = __shfl((int)p1, srcbase + 16);
            if (active) {
                uint4 v = {g0, g1, g2, g3};
                int t_o = 2 * wv + t;
                *(uint4*)(hb + (jtg * 8 + t_o) * 512 + l * 8) = v;
            }
        }
    }
}

// ---------------- Kernel B: fused adj-masked softmax attention + PV (MFMA) ----------------
// grid = B*N/16 = 512 blocks, 512 threads (8 waves).
// Wave wv handles j-tiles jt = wv + 8*it (it=0..7, FULLY unrolled), all 8 o-tiles.
// adj read DIRECTLY (no mask pre-pass) with an explicit 1-tile-ahead register
// pipeline: next tile's 2 dwordx4 loads issue before current tile's compute, so
// the ~900-cycle HBM latency hides under hf(L2)+exp2+MFMA work across 16 waves/CU.
// No online max (logits bounded in log2 domain; masked -> p=0 exactly).
__global__ void __launch_bounds__(512, 4) k_attn(const int* __restrict__ adj,
                                                 const int* __restrict__ d1p,
                                                 const int* __restrict__ d2p,
                                                 const float* __restrict__ t1g,
                                                 const float* __restrict__ t2g,
                                                 const unsigned short* __restrict__ hb,
                                                 float* __restrict__ out) {
    __shared__ __align__(16) float accbuf[4][16][132];   // 33792 B
    __shared__ float lds_s[8][16];
    __shared__ float lds_inv[16];

    int blk = blockIdx.x;
    int b = blk >> 7;
    int i0 = (blk & 127) * 16;
    int tid = threadIdx.x;
    int wv = tid >> 6;            // 0..7
    int l = tid & 63;
    int lr = l & 15, lg = l >> 4;
    int d1 = d1p[0], d2 = d2p[0];

    float t1v = t1g[b * NN + i0 + lr];                       // pre-scaled by log2e
    const float* t2p = t2g + b * NN + lg * 8;                // pre-scaled by log2e
    const unsigned short* hbbase = hb + (size_t)b * 64 * 4096 + (size_t)l * 8;
    const int* adjRow = adj + ((size_t)(b * NN + i0 + lr)) * NN + lg * 8;

    float s = 0.f;
    f32x4 acc[8];
#pragma unroll
    for (int t = 0; t < 8; t++) acc[t] = (f32x4){0.f, 0.f, 0.f, 0.f};

    // prologue: tile jt0 = wv in flight
    int4 cA = *(const int4*)(adjRow + wv * 32);
    int4 cB = *(const int4*)(adjRow + wv * 32 + 4);

#pragma unroll
    for (int it = 0; it < 8; it++) {
        int jt = wv + it * 8;
        // issue next tile's adj loads FIRST (1-ahead pipeline; static branch)
        int4 nA = cA, nB = cB;
        if (it < 7) {
            nA = *(const int4*)(adjRow + (jt + 8) * 32);
            nB = *(const int4*)(adjRow + (jt + 8) * 32 + 4);
        }
        float4 tb0 = *(const float4*)(t2p + jt * 32);
        float4 tb1 = *(const float4*)(t2p + jt * 32 + 4);
        bf16x8 hf[8];
#pragma unroll
        for (int t = 0; t < 8; t++)
            hf[t] = *(const bf16x8*)(hbbase + (size_t)jt * 4096 + t * 512);

        int ai[8] = {cA.x, cA.y, cA.z, cA.w, cB.x, cB.y, cB.z, cB.w};
        float tv[8] = {tb0.x, tb0.y, tb0.z, tb0.w, tb1.x, tb1.y, tb1.z, tb1.w};
        float p[8];
        float psum = 0.f;
#pragma unroll
        for (int jj = 0; jj < 8; jj++) {
            float v = t1v + tv[jj];
            float e = fmaxf(v, ALPHAV * v);              // leaky relu (log2 domain)
            float ex = __builtin_amdgcn_exp2f(e);
            p[jj] = (ai[jj] == d1 || ai[jj] == d2) ? ex : 0.f;
            psum += p[jj];
        }
        s += psum;

        unsigned u[4];
#pragma unroll
        for (int w = 0; w < 4; w++) u[w] = cvt_pk_bf16(p[2 * w], p[2 * w + 1]);
        bf16x8 pa = *(const bf16x8*)u;
#pragma unroll
        for (int t = 0; t < 8; t++)
            acc[t] = __builtin_amdgcn_mfma_f32_16x16x32_bf16(pa, hf[t], acc[t], 0, 0, 0);

        cA = nA; cB = nB;
    }

    // ---- cross-wave sum combine ----
    s += __shfl_xor(s, 16);
    s += __shfl_xor(s, 32);
    if (l < 16) lds_s[wv][lr] = s;

    if (wv < 4) {
#pragma unroll
        for (int t = 0; t < 8; t++)
#pragma unroll
            for (int r = 0; r < 4; r++)
                accbuf[wv][lg * 4 + r][t * 16 + lr] = acc[t][r];
    }
    __syncthreads();
    if (wv >= 4) {
#pragma unroll
        for (int t = 0; t < 8; t++)
#pragma unroll
            for (int r = 0; r < 4; r++)
                accbuf[wv - 4][lg * 4 + r][t * 16 + lr] += acc[t][r];
    }
    if (tid < 16) {
        float st = 0.f;
#pragma unroll
        for (int w = 0; w < 8; w++) st += lds_s[w][tid];
        lds_inv[tid] = 1.0f / st;
    }
    __syncthreads();

    {
        int row = tid >> 5;
        int c4 = (tid & 31) * 4;
        float4 s0 = *(const float4*)&accbuf[0][row][c4];
        float4 s1 = *(const float4*)&accbuf[1][row][c4];
        float4 s2 = *(const float4*)&accbuf[2][row][c4];
        float4 s3 = *(const float4*)&accbuf[3][row][c4];
        float inv = lds_inv[row];
        float4 o;
        o.x = (s0.x + s1.x + s2.x + s3.x) * inv;
        o.y = (s0.y + s1.y + s2.y + s3.y) * inv;
        o.z = (s0.z + s1.z + s2.z + s3.z) * inv;
        o.w = (s0.w + s1.w + s2.w + s3.w) * inv;
        *(float4*)&out[((size_t)b * NN + i0 + row) * FOUT + c4] = o;
    }
}

extern "C" void kernel_launch(void* const* d_in, const int* in_sizes, int n_in,
                              void* d_out, int out_size, void* d_ws, size_t ws_size,
                              hipStream_t stream) {
    const float* x  = (const float*)d_in[0];
    const float* W  = (const float*)d_in[1];
    const float* a1 = (const float*)d_in[2];
    const float* a2 = (const float*)d_in[3];
    const int* adj  = (const int*)d_in[4];
    // d_in[5] = adj_tree (unused by reference forward)
    const int* d1p  = (const int*)d_in[6];
    const int* d2p  = (const int*)d_in[7];
    float* out = (float*)d_out;

    char* ws = (char*)d_ws;
    unsigned short* hbuf = (unsigned short*)(ws);                       // 2 MB
    float* t1            = (float*)(ws + 2u * 1024 * 1024);             // 32 KB
    float* t2            = (float*)(ws + 2u * 1024 * 1024 + 32 * 1024); // 32 KB
    unsigned short* whi  = (unsigned short*)(ws + 2u * 1024 * 1024 + 64 * 1024);  // 128 KB
    unsigned short* wlo  = (unsigned short*)(ws + 2u * 1024 * 1024 + 192 * 1024); // 128 KB

    k_wrep<<<dim3(128), dim3(64), 0, stream>>>(W, whi, wlo);
    k_h<<<dim3(512), dim3(256), 0, stream>>>(x, whi, wlo, a1, a2, hbuf, t1, t2);
    k_attn<<<dim3(512), dim3(512), 0, stream>>>(adj, d1p, d2p, t1, t2, hbuf, out);
}